// Round 3
// baseline (564.821 us; speedup 1.0000x reference)
//
#include <hip/hip_runtime.h>
#include <cstdint>
#include <cstddef>

// ---------------- problem constants (mirror reference) ----------------
#define BB      8
#define AA      6
#define CCL     16          // classes
#define HH      160
#define WWW     160
#define HWSZ    (HH * WWW)          // 25600
#define NN      (AA * HWSZ)         // 153600 boxes per image
#define NBLK    (NN / 256)          // 600 blocks per image
#define PRE_K   2000
#define P2      2048                // padded PRE_K
#define CAP     4096                // compaction capacity per image
#define POST_K  100
#define SCORE_THR 0.05f
#define IOU_THR   0.5f
#define DW_CLAMP  4.0f
#define IMG_WF    1280.0f
#define IMG_HF    1280.0f
#define MIN_WF    2.0f
#define MIN_HF    2.0f

typedef unsigned int       u32;
typedef unsigned long long u64;

// ---------------- shared decode (must match reference arithmetic) ------
// sigmoid is monotone -> argmax over logits == argmax over probs, and
// max prob == sigmoid(max logit). One expf+div instead of 16.
__device__ __forceinline__ void decode_one(const float* __restrict__ anchors,
                                           const float* __restrict__ head,
                                           int b, int n,
                                           float4& box, float& score, int& cls,
                                           bool& valid) {
    int a  = n / HWSZ;
    int hw = n - a * HWSZ;
    const float* hp = head + (((size_t)b * AA + a) * (4 + CCL)) * HWSZ + hw;
    float d0 = hp[0];
    float d1 = hp[(size_t)1 * HWSZ];
    float d2 = hp[(size_t)2 * HWSZ];
    float d3 = hp[(size_t)3 * HWSZ];

    // argmax over raw logits, first-max tie semantics (strict >)
    float bl = -1e30f; int bc = 0;
    #pragma unroll
    for (int k = 0; k < CCL; ++k) {
        float l = hp[(size_t)(4 + k) * HWSZ];
        if (l > bl) { bl = l; bc = k; }
    }
    float best = 1.0f / (1.0f + expf(-bl));   // IEEE div, accurate expf

    const float* ap = anchors + (size_t)a * 4 * HWSZ + hw;
    float ax1 = ap[0];
    float ay1 = ap[(size_t)1 * HWSZ];
    float ax2 = ap[(size_t)2 * HWSZ];
    float ay2 = ap[(size_t)3 * HWSZ];
    float aw  = ax2 - ax1;
    float ah  = ay2 - ay1;
    float acx = ax1 + 0.5f * aw;
    float acy = ay1 + 0.5f * ah;

    float dw = fminf(d2, DW_CLAMP);
    float dh = fminf(d3, DW_CLAMP);
    float gcx = acx + d0 * aw;
    float gcy = acy + d1 * ah;
    float gw  = aw * expf(dw);
    float gh  = ah * expf(dh);

    float x1 = fminf(fmaxf(gcx - 0.5f * gw, 0.0f), IMG_WF);
    float x2 = fminf(fmaxf(gcx + 0.5f * gw, 0.0f), IMG_WF);
    float y1 = fminf(fmaxf(gcy - 0.5f * gh, 0.0f), IMG_HF);
    float y2 = fminf(fmaxf(gcy + 0.5f * gh, 0.0f), IMG_HF);

    valid = (best >= SCORE_THR) && ((x2 - x1) >= MIN_WF) && ((y2 - y1) >= MIN_HF);
    box = make_float4(x1, y1, x2, y2);
    score = best;
    cls = bc;
}

// ---------------- K0: zero ws control region -------------------------
// u32 idx: hist[3*8*256] @0; prefix[8] @6144; need[8] @6152; ccnt[8] @6160
__global__ void init_kernel(u32* __restrict__ w) {
    int tid = threadIdx.x;
    for (int i = tid; i < 6168; i += 256) w[i] = 0u;
    __syncthreads();
    if (tid < BB) w[6152 + tid] = PRE_K;
}

// ---------------- K1: decode + key write + level-0 histogram ---------
__global__ void __launch_bounds__(256) decode_kernel(const float* __restrict__ anchors,
                                                     const float* __restrict__ head,
                                                     u32* __restrict__ keys,
                                                     u32* __restrict__ hist1) {
    __shared__ u32 h[256];
    int tid = threadIdx.x;
    h[tid] = 0u;
    __syncthreads();
    int blk = blockIdx.x;
    int b = blk / NBLK;
    int n = (blk - b * NBLK) * 256 + tid;

    float4 box; float sc; int cl; bool valid;
    decode_one(anchors, head, b, n, box, sc, cl, valid);
    u32 key = valid ? __float_as_uint(sc) : 0u;   // score>0 -> bits monotone
    keys[(size_t)b * NN + n] = key;
    if (key) atomicAdd(&h[key >> 24], 1u);
    __syncthreads();
    if (h[tid]) atomicAdd(&hist1[b * 256 + tid], h[tid]);
}

// ---------------- histogram of one refinement digit ------------------
__global__ void __launch_bounds__(256) hist_kernel(const u32* __restrict__ keys,
                                                   const u32* __restrict__ prefix,
                                                   u32* __restrict__ hist,
                                                   u32 pmask, int shift) {
    __shared__ u32 h[256];
    int tid = threadIdx.x;
    h[tid] = 0u;
    __syncthreads();
    int blk = blockIdx.x;
    int b = blk / NBLK;
    int n = (blk - b * NBLK) * 256 + tid;
    u32 key = keys[(size_t)b * NN + n];
    u32 pfx = prefix[b];
    if (key != 0u && (key & pmask) == (pfx & pmask))
        atomicAdd(&h[(key >> shift) & 255u], 1u);
    __syncthreads();
    if (h[tid]) atomicAdd(&hist[b * 256 + tid], h[tid]);
}

// ---------------- pick digit where descending cumsum crosses `need` ---
__global__ void select_kernel(const u32* __restrict__ hist,
                              u32* __restrict__ prefix, u32* __restrict__ need,
                              int shift) {
    if (threadIdx.x != 0) return;
    int b = blockIdx.x;
    const u32* h = hist + b * 256;
    u32 nd = need[b];
    u32 cum = 0; int d = 0;
    for (int e = 255; e > 0; --e) {
        u32 c = h[e];
        if (cum + c >= nd) { d = e; break; }
        cum += c;
    }
    prefix[b] |= ((u32)d) << shift;
    need[b] = nd - cum;   // remaining needed inside chosen bin
}

// ---------------- compact keys >= threshold --------------------------
__global__ void __launch_bounds__(256) compact_kernel(const u32* __restrict__ keys,
                                                      const u32* __restrict__ prefix,
                                                      u32* __restrict__ ccnt,
                                                      u64* __restrict__ cand) {
    int blk = blockIdx.x;
    int b = blk / NBLK;
    int n = (blk - b * NBLK) * 256 + threadIdx.x;
    u32 key = keys[(size_t)b * NN + n];
    u32 T = prefix[b];
    if (key != 0u && key >= T) {
        u32 pos = atomicAdd(&ccnt[b], 1u);
        if (pos < CAP)
            cand[(size_t)b * CAP + pos] =
                ((u64)key << 32) | (u32)(~(u32)n);   // key desc, idx asc when sorted desc
    }
}

// ---------------- bitonic sort 4096 u64 in LDS (ascending on ~v) -----
__global__ void __launch_bounds__(1024) sort_kernel(const u64* __restrict__ cand,
                                                    const u32* __restrict__ ccnt,
                                                    u64* __restrict__ sel) {
    __shared__ u64 sm[CAP];
    int b = blockIdx.x, tid = threadIdx.x;
    u32 n = ccnt[b]; if (n > CAP) n = CAP;
    for (int i = tid; i < CAP; i += 1024)
        sm[i] = (i < (int)n) ? ~cand[(size_t)b * CAP + i] : ~0ULL;
    __syncthreads();
    for (int k = 2; k <= CAP; k <<= 1) {
        for (int j = k >> 1; j > 0; j >>= 1) {
            for (int i = tid; i < CAP; i += 1024) {
                int ixj = i ^ j;
                if (ixj > i) {
                    u64 a = sm[i], c = sm[ixj];
                    bool up = ((i & k) == 0);
                    if (up ? (a > c) : (a < c)) { sm[i] = c; sm[ixj] = a; }
                }
            }
            __syncthreads();
        }
    }
    for (int r = tid; r < P2; r += 1024)
        sel[(size_t)b * P2 + r] = ~sm[r];
}

// ---------------- gather-decode the selected 2000 --------------------
__global__ void __launch_bounds__(256) gather_kernel(const float* __restrict__ anchors,
                                                     const float* __restrict__ head,
                                                     const u64* __restrict__ sel,
                                                     float4* __restrict__ topbox,
                                                     float* __restrict__ tops,
                                                     int* __restrict__ topcls) {
    int b = blockIdx.x >> 3;
    int r = (blockIdx.x & 7) * 256 + threadIdx.x;
    u64 v = sel[(size_t)b * P2 + r];
    float4 box = make_float4(0.f, 0.f, 0.f, 0.f);
    float sc = -1.0f; int cl = 0;
    if (v != 0ULL && r < PRE_K) {   // ranks >= PRE_K are outside ref's top_k
        int n = (int)(~(u32)v);
        bool valid;
        decode_one(anchors, head, b, n, box, sc, cl, valid);
    }
    topbox[(size_t)b * P2 + r] = box;
    tops  [(size_t)b * P2 + r] = sc;
    topcls[(size_t)b * P2 + r] = cl;
}

// ---------------- suppression bitmask: mask[i][w] bits over j --------
__global__ void __launch_bounds__(256) mask_kernel(const float4* __restrict__ topbox,
                                                   const float* __restrict__ tops,
                                                   u64* __restrict__ mask) {
    __shared__ float4 bx[P2];      // 32 KB
    __shared__ float2 sa[P2];      // (score, area) 16 KB
    int b    = blockIdx.x >> 5;
    int rblk = blockIdx.x & 31;    // 64 rows per block
    int tid  = threadIdx.x;
    for (int i = tid; i < P2; i += 256) {
        float4 bb = topbox[(size_t)b * P2 + i];
        bx[i] = bb;
        sa[i] = make_float2(tops[(size_t)b * P2 + i],
                            (bb.z - bb.x) * (bb.w - bb.y));
    }
    __syncthreads();
    int i  = rblk * 64 + (tid >> 2);
    int w0 = (tid & 3) * 8;
    float4 bi = bx[i];
    float  si = sa[i].x;
    float  ai = sa[i].y;
    for (int w = w0; w < w0 + 8; ++w) {
        u64 bits = 0ULL;
        #pragma unroll 8
        for (int jj = 0; jj < 64; ++jj) {
            int j = w * 64 + jj;
            float4 bj = bx[j];
            float2 sj = sa[j];
            float iw = fminf(bi.z, bj.z) - fmaxf(bi.x, bj.x);
            float ih = fminf(bi.w, bj.w) - fmaxf(bi.y, bj.y);
            iw = fmaxf(iw, 0.0f); ih = fmaxf(ih, 0.0f);
            float inter = iw * ih;
            float uni = fmaxf(ai + sj.y - inter, 1e-9f);
            float iou = inter / uni;                       // ref divides
            if (iou > IOU_THR && si > sj.x) bits |= (1ULL << jj);
        }
        mask[((size_t)b * P2 + i) * 32 + w] = bits;
    }
}

// ---------------- sequential greedy scan, 1 wave per image -----------
// Suppression is forward-only (descending scores + strict >), so a single
// ascending sweep over i reproduces the reference fori_loop exactly.
__global__ void __launch_bounds__(64) nms_scan_kernel(const u64* __restrict__ sel,
                                                      const u64* __restrict__ mask,
                                                      u64* __restrict__ keepout) {
    int b = blockIdx.x;
    int lane = threadIdx.x;          // lanes 0..31 own the 32 keep words
    if (lane < 32) {
        u64 keep = 0ULL;
        for (int j = 0; j < 64; ++j) {
            int idx = lane * 64 + j;
            u64 v = sel[(size_t)b * P2 + idx];
            if (idx < PRE_K && v != 0ULL) keep |= (1ULL << j);
        }
        const u64* mrow = mask + (size_t)b * P2 * 32 + lane;
        u64 bufA[32], bufB[32];
        #pragma unroll
        for (int k = 0; k < 32; ++k) bufA[k] = mrow[(size_t)k * 32];

        for (int cc = 0; cc < 32; ++cc) {
            int c0 = 2 * cc, c1 = 2 * cc + 1;
            // prefetch chunk c1 (overlaps with processing c0)
            #pragma unroll
            for (int k = 0; k < 32; ++k)
                bufB[k] = mrow[(size_t)(c1 * 32 + k) * 32];
            #pragma unroll
            for (int k = 0; k < 32; ++k) {
                int i = c0 * 32 + k;
                u64 kw = __shfl(keep, i >> 6);
                if ((kw >> (i & 63)) & 1ULL) keep &= ~bufA[k];
            }
            // prefetch chunk c0+2 (clamped) overlapping with processing c1
            int cn = (c0 + 2 < 64) ? (c0 + 2) : 63;
            #pragma unroll
            for (int k = 0; k < 32; ++k)
                bufA[k] = mrow[(size_t)(cn * 32 + k) * 32];
            #pragma unroll
            for (int k = 0; k < 32; ++k) {
                int i = c1 * 32 + k;
                u64 kw = __shfl(keep, i >> 6);
                if ((kw >> (i & 63)) & 1ULL) keep &= ~bufB[k];
            }
        }
        keepout[b * 32 + lane] = keep;
    }
}

// ---------------- final top-100 compaction + zero pad ----------------
__global__ void __launch_bounds__(256) out_kernel(const u64* __restrict__ keepw,
                                                  const float4* __restrict__ topbox,
                                                  const float* __restrict__ tops,
                                                  const int* __restrict__ topcls,
                                                  float* __restrict__ out) {
    __shared__ u64 kw[32];
    __shared__ u32 pre[32];
    int b = blockIdx.x, tid = threadIdx.x;
    if (tid < 32) kw[tid] = keepw[b * 32 + tid];
    __syncthreads();
    if (tid == 0) {
        u32 c = 0;
        for (int w = 0; w < 32; ++w) { pre[w] = c; c += (u32)__popcll(kw[w]); }
    }
    __syncthreads();
    float* ob = out;                          // [B][100][4]
    float* os = out + BB * POST_K * 4;        // [B][100]
    float* oc = out + BB * POST_K * 5;        // [B][100] (cls as float)
    if (tid < POST_K) {
        int base = b * POST_K + tid;
        ob[base * 4 + 0] = 0.f; ob[base * 4 + 1] = 0.f;
        ob[base * 4 + 2] = 0.f; ob[base * 4 + 3] = 0.f;
        os[base] = 0.f; oc[base] = 0.f;
    }
    __syncthreads();
    for (int i = tid; i < P2; i += 256) {
        int w = i >> 6, bit = i & 63;
        u64 word = kw[w];
        if ((word >> bit) & 1ULL) {
            u32 rank = pre[w] + (u32)__popcll(word & ((1ULL << bit) - 1ULL));
            if (rank < POST_K) {
                float4 bb = topbox[(size_t)b * P2 + i];
                int base = b * POST_K + (int)rank;
                ob[base * 4 + 0] = bb.x; ob[base * 4 + 1] = bb.y;
                ob[base * 4 + 2] = bb.z; ob[base * 4 + 3] = bb.w;
                os[base] = tops[(size_t)b * P2 + i];
                oc[base] = (float)topcls[(size_t)b * P2 + i];
            }
        }
    }
}

// ---------------- host launch ----------------------------------------
extern "C" void kernel_launch(void* const* d_in, const int* in_sizes, int n_in,
                              void* d_out, int out_size, void* d_ws, size_t ws_size,
                              hipStream_t stream) {
    (void)in_sizes; (void)n_in; (void)out_size; (void)ws_size;
    const float* anchors = (const float*)d_in[0];
    const float* head    = (const float*)d_in[1];
    float* out = (float*)d_out;
    char* ws = (char*)d_ws;

    // workspace layout (peak ≈5.73 MB).
    // NOTE: mask ALIASES keys — keys' last read is compact_kernel, mask's
    // first write is mask_kernel (strictly later in-stream). Saves 4.2 MB.
    u32* hist    = (u32*)(ws + 0);              // 3 levels * 8 * 256
    u32* prefix  = (u32*)(ws + 24576);          // 8
    u32* need    = (u32*)(ws + 24608);          // 8
    u32* ccnt    = (u32*)(ws + 24640);          // 8
    u32* keys    = (u32*)(ws + 24832);          // 8*153600*4 B
    u64* mask    = (u64*)(ws + 24832);          // 8*2048*32*8 B (aliases keys)
    u64* cand    = (u64*)(ws + 4940032);        // 8*4096
    u64* sel     = (u64*)(ws + 5202176);        // 8*2048
    float4* topbox = (float4*)(ws + 5333248);   // 8*2048
    float* tops  = (float*)(ws + 5595392);      // 8*2048
    int* topcls  = (int*)(ws + 5660928);        // 8*2048
    u64* keepw   = (u64*)(ws + 5726464);        // 8*32

    init_kernel<<<1, 256, 0, stream>>>((u32*)ws);
    decode_kernel<<<BB * NBLK, 256, 0, stream>>>(anchors, head, keys, hist);
    select_kernel<<<BB, 64, 0, stream>>>(hist, prefix, need, 24);
    hist_kernel<<<BB * NBLK, 256, 0, stream>>>(keys, prefix, hist + BB * 256,
                                               0xFF000000u, 16);
    select_kernel<<<BB, 64, 0, stream>>>(hist + BB * 256, prefix, need, 16);
    hist_kernel<<<BB * NBLK, 256, 0, stream>>>(keys, prefix, hist + 2 * BB * 256,
                                               0xFFFF0000u, 8);
    select_kernel<<<BB, 64, 0, stream>>>(hist + 2 * BB * 256, prefix, need, 8);
    compact_kernel<<<BB * NBLK, 256, 0, stream>>>(keys, prefix, ccnt, cand);
    sort_kernel<<<BB, 1024, 0, stream>>>(cand, ccnt, sel);
    gather_kernel<<<BB * 8, 256, 0, stream>>>(anchors, head, sel, topbox, tops, topcls);
    mask_kernel<<<BB * 32, 256, 0, stream>>>(topbox, tops, mask);
    nms_scan_kernel<<<BB, 64, 0, stream>>>(sel, mask, keepw);
    out_kernel<<<BB, 256, 0, stream>>>(keepw, topbox, tops, topcls, out);
}

// Round 5
// 437.830 us; speedup vs baseline: 1.2900x; 1.2900x over previous
//
#include <hip/hip_runtime.h>
#include <cstdint>
#include <cstddef>

// ---------------- problem constants (mirror reference) ----------------
#define BB      8
#define AA      6
#define CCL     16          // classes
#define HH      160
#define WWW     160
#define HWSZ    (HH * WWW)          // 25600
#define NN      (AA * HWSZ)         // 153600 boxes per image
#define NBLK    (NN / 256)          // 600 blocks per image (scalar passes)
#define NBLK4   (NN / 1024)         // 150 blocks per image (float4 decode)
#define PRE_K   2000
#define P2      2048                // padded PRE_K
#define CAP     4096                // compaction capacity per image
#define POST_K  100
#define SCORE_THR 0.05f
#define IOU_THR   0.5f
#define DW_CLAMP  4.0f
#define IMG_WF    1280.0f
#define IMG_HF    1280.0f
#define MIN_WF    2.0f
#define MIN_HF    2.0f

#define CCNT_STRIDE 32      // pad per-image atomic counters to 128 B (own line)

typedef unsigned int       u32;
typedef unsigned long long u64;

// ---------------- K0: zero ws control region -------------------------
// u32 idx: hist[3*8*256] @0; prefix[8] @6144; need[8] @6152;
//          ccnt[8*CCNT_STRIDE] @6160  (end 6416)
__global__ void init_kernel(u32* __restrict__ w) {
    int tid = threadIdx.x;
    for (int i = tid; i < 6416; i += 256) w[i] = 0u;
    __syncthreads();
    if (tid < BB) w[6152 + tid] = PRE_K;
}

// ---------------- K1: float4 decode + key write + level-0 histogram --
// sigmoid is monotone: max prob = sigmoid(max logit); cls is NOT needed
// here (only gather needs it), so a plain fmaxf chain suffices.
__global__ void __launch_bounds__(256) decode_kernel(const float* __restrict__ anchors,
                                                     const float* __restrict__ head,
                                                     u32* __restrict__ keys,
                                                     u32* __restrict__ hist1) {
    __shared__ u32 h[256];
    int tid = threadIdx.x;
    h[tid] = 0u;
    __syncthreads();
    int blk = blockIdx.x;
    int b  = blk / NBLK4;
    int e0 = ((blk - b * NBLK4) * 256 + tid) * 4;   // 4 consecutive hw cells
    int a  = e0 / HWSZ;                              // all 4 in same channel row
    int hw = e0 - a * HWSZ;
    const int CS = HWSZ / 4;                         // float4 channel stride
    const float4* hp = (const float4*)(head +
        (((size_t)b * AA + a) * (4 + CCL)) * HWSZ + hw);
    const float4* ap = (const float4*)(anchors + (size_t)a * 4 * HWSZ + hw);

    float4 d0 = hp[0];
    float4 d1 = hp[CS];
    float4 d2 = hp[2 * CS];
    float4 d3 = hp[3 * CS];

    float4 bl = make_float4(-1e30f, -1e30f, -1e30f, -1e30f);
    #pragma unroll
    for (int k = 0; k < CCL; ++k) {
        float4 lv = hp[(4 + k) * CS];
        bl.x = fmaxf(bl.x, lv.x);
        bl.y = fmaxf(bl.y, lv.y);
        bl.z = fmaxf(bl.z, lv.z);
        bl.w = fmaxf(bl.w, lv.w);
    }

    float4 ax1 = ap[0];
    float4 ay1 = ap[CS];
    float4 ax2 = ap[2 * CS];
    float4 ay2 = ap[3 * CS];

    u32 k4[4];
    #pragma unroll
    for (int j = 0; j < 4; ++j) {
        float dj0 = (&d0.x)[0 * 4 + j]; // float4 members are contiguous
        float dj1 = (&d1.x)[j];
        float dj2 = (&d2.x)[j];
        float dj3 = (&d3.x)[j];
        float x1a = (&ax1.x)[j], y1a = (&ay1.x)[j];
        float x2a = (&ax2.x)[j], y2a = (&ay2.x)[j];
        float blj = (&bl.x)[j];

        float best = 1.0f / (1.0f + expf(-blj));   // IEEE div, accurate expf

        float aw  = x2a - x1a;
        float ah  = y2a - y1a;
        float acx = x1a + 0.5f * aw;
        float acy = y1a + 0.5f * ah;
        float dw = fminf(dj2, DW_CLAMP);
        float dh = fminf(dj3, DW_CLAMP);
        float gcx = acx + dj0 * aw;
        float gcy = acy + dj1 * ah;
        float gw  = aw * expf(dw);
        float gh  = ah * expf(dh);
        float x1 = fminf(fmaxf(gcx - 0.5f * gw, 0.0f), IMG_WF);
        float x2 = fminf(fmaxf(gcx + 0.5f * gw, 0.0f), IMG_WF);
        float y1 = fminf(fmaxf(gcy - 0.5f * gh, 0.0f), IMG_HF);
        float y2 = fminf(fmaxf(gcy + 0.5f * gh, 0.0f), IMG_HF);

        bool valid = (best >= SCORE_THR) && ((x2 - x1) >= MIN_WF) &&
                     ((y2 - y1) >= MIN_HF);
        k4[j] = valid ? __float_as_uint(best) : 0u;  // score>0 -> bits monotone
    }

    *(uint4*)(keys + (size_t)b * NN + e0) = make_uint4(k4[0], k4[1], k4[2], k4[3]);

    // per-thread bin merge (scores concentrate in ~3 top-byte bins)
    #pragma unroll
    for (int j = 0; j < 4; ++j) {
        if (!k4[j]) continue;
        u32 bin = k4[j] >> 24;
        bool dup = false;
        #pragma unroll
        for (int l = 0; l < 4; ++l)
            if (l < j) dup |= (k4[l] != 0u) && ((k4[l] >> 24) == bin);
        if (!dup) {
            u32 c = 1;
            #pragma unroll
            for (int l = 0; l < 4; ++l)
                if (l > j) c += ((k4[l] != 0u) && ((k4[l] >> 24) == bin)) ? 1u : 0u;
            atomicAdd(&h[bin], c);
        }
    }
    __syncthreads();
    if (h[tid]) atomicAdd(&hist1[b * 256 + tid], h[tid]);
}

// ---------------- histogram of one refinement digit ------------------
__global__ void __launch_bounds__(256) hist_kernel(const u32* __restrict__ keys,
                                                   const u32* __restrict__ prefix,
                                                   u32* __restrict__ hist,
                                                   u32 pmask, int shift) {
    __shared__ u32 h[256];
    int tid = threadIdx.x;
    h[tid] = 0u;
    __syncthreads();
    int blk = blockIdx.x;
    int b = blk / NBLK;
    int n = (blk - b * NBLK) * 256 + tid;
    u32 key = keys[(size_t)b * NN + n];
    u32 pfx = prefix[b];
    if (key != 0u && (key & pmask) == (pfx & pmask))
        atomicAdd(&h[(key >> shift) & 255u], 1u);
    __syncthreads();
    if (h[tid]) atomicAdd(&hist[b * 256 + tid], h[tid]);
}

// ---------------- pick digit where descending cumsum crosses `need` ---
// Parallel (256 thr) but bit-identical semantics to the serial loop:
//   cum=0; for e=255..1 { c=h[e]; if (cum+c>=nd) {d=e;break;} cum+=c; }
//   prefix|=d<<shift; need=nd-cum
// Via inclusive suffix sums U[e]=sum_{e'>=e} c[e']:
//   d = largest e in [1,255] with U[e] >= nd (else 0)
//   break case: need = nd-(U[d]-c[d]);  no-break: need = nd-U[1]
__global__ void __launch_bounds__(256) select_kernel(const u32* __restrict__ hist,
                                                     u32* __restrict__ prefix,
                                                     u32* __restrict__ need,
                                                     int shift) {
    __shared__ u32 a[256];
    __shared__ int best;
    int t = threadIdx.x;
    int b = blockIdx.x;
    u32 nd = need[b];
    u32 myc = hist[b * 256 + t];
    a[t] = myc;
    if (t == 0) best = 0;
    __syncthreads();
    // Hillis-Steele inclusive suffix scan
    for (int s = 1; s < 256; s <<= 1) {
        u32 v = a[t] + ((t + s < 256) ? a[t + s] : 0u);
        __syncthreads();
        a[t] = v;
        __syncthreads();
    }
    if (t >= 1 && a[t] >= nd) atomicMax(&best, t);
    __syncthreads();
    if (t == best) {
        if (t >= 1) {
            prefix[b] |= ((u32)t) << shift;
            need[b] = nd - (a[t] - myc);
        } else {
            need[b] = nd - a[1];   // no bin e>=1 crossed: d=0, cum = U[1]
        }
    }
}

// ---------------- compact keys >= threshold --------------------------
// One global atomic per block (ballot-rank within wave, LDS across waves).
__global__ void __launch_bounds__(256) compact_kernel(const u32* __restrict__ keys,
                                                      const u32* __restrict__ prefix,
                                                      u32* __restrict__ ccnt,
                                                      u64* __restrict__ cand) {
    __shared__ u32 swcnt[4];
    __shared__ u32 soff[4];
    __shared__ u32 sbase;
    int blk = blockIdx.x;
    int b = blk / NBLK;
    int tid = threadIdx.x;
    int n = (blk - b * NBLK) * 256 + tid;
    u32 key = keys[(size_t)b * NN + n];
    u32 T = prefix[b];
    bool pred = (key != 0u) && (key >= T);
    u64 bal = __ballot(pred);
    int lane = tid & 63;
    u32 rank = (u32)__popcll(bal & ((1ull << lane) - 1ull));
    int wid = tid >> 6;
    if (lane == 0) swcnt[wid] = (u32)__popcll(bal);
    __syncthreads();
    if (tid == 0) {
        u32 c0 = swcnt[0], c1 = swcnt[1], c2 = swcnt[2], c3 = swcnt[3];
        soff[0] = 0; soff[1] = c0; soff[2] = c0 + c1; soff[3] = c0 + c1 + c2;
        u32 tot = c0 + c1 + c2 + c3;
        sbase = tot ? atomicAdd(&ccnt[b * CCNT_STRIDE], tot) : 0u;
    }
    __syncthreads();
    if (pred) {
        u32 pos = sbase + soff[wid] + rank;
        if (pos < CAP)
            cand[(size_t)b * CAP + pos] =
                ((u64)key << 32) | (u32)(~(u32)n);   // key desc, idx asc when sorted desc
    }
}

// ---------------- bitonic sort 4096 u64 in LDS (ascending on ~v) -----
__global__ void __launch_bounds__(1024) sort_kernel(const u64* __restrict__ cand,
                                                    const u32* __restrict__ ccnt,
                                                    u64* __restrict__ sel) {
    __shared__ u64 sm[CAP];
    int b = blockIdx.x, tid = threadIdx.x;
    u32 n = ccnt[b * CCNT_STRIDE]; if (n > CAP) n = CAP;
    for (int i = tid; i < CAP; i += 1024)
        sm[i] = (i < (int)n) ? ~cand[(size_t)b * CAP + i] : ~0ULL;
    __syncthreads();
    for (int k = 2; k <= CAP; k <<= 1) {
        for (int j = k >> 1; j > 0; j >>= 1) {
            for (int i = tid; i < CAP; i += 1024) {
                int ixj = i ^ j;
                if (ixj > i) {
                    u64 a = sm[i], c = sm[ixj];
                    bool up = ((i & k) == 0);
                    if (up ? (a > c) : (a < c)) { sm[i] = c; sm[ixj] = a; }
                }
            }
            __syncthreads();
        }
    }
    for (int r = tid; r < P2; r += 1024)
        sel[(size_t)b * P2 + r] = ~sm[r];
}

// ---------------- gather-decode the selected 2000 --------------------
// score comes FROM the key bits (bit-identical to sort order); box & cls
// are decoded fresh (reference-identical expressions).
__global__ void __launch_bounds__(256) gather_kernel(const float* __restrict__ anchors,
                                                     const float* __restrict__ head,
                                                     const u64* __restrict__ sel,
                                                     float4* __restrict__ topbox,
                                                     float* __restrict__ tops,
                                                     int* __restrict__ topcls) {
    int b = blockIdx.x >> 3;
    int r = (blockIdx.x & 7) * 256 + threadIdx.x;
    u64 v = sel[(size_t)b * P2 + r];
    float4 box = make_float4(0.f, 0.f, 0.f, 0.f);
    float sc = -1.0f; int cl = 0;
    if (v != 0ULL && r < PRE_K) {   // ranks >= PRE_K are outside ref's top_k
        int n = (int)(~(u32)v);
        sc = __uint_as_float((u32)(v >> 32));

        int a  = n / HWSZ;
        int hw = n - a * HWSZ;
        const float* hp = head + (((size_t)b * AA + a) * (4 + CCL)) * HWSZ + hw;
        float d0 = hp[0];
        float d1 = hp[(size_t)1 * HWSZ];
        float d2 = hp[(size_t)2 * HWSZ];
        float d3 = hp[(size_t)3 * HWSZ];

        // argmax over raw logits, first-max tie semantics (strict >)
        float blv = -1e30f; int bc = 0;
        #pragma unroll
        for (int k = 0; k < CCL; ++k) {
            float l = hp[(size_t)(4 + k) * HWSZ];
            if (l > blv) { blv = l; bc = k; }
        }
        cl = bc;

        const float* ap = anchors + (size_t)a * 4 * HWSZ + hw;
        float ax1 = ap[0];
        float ay1 = ap[(size_t)1 * HWSZ];
        float ax2 = ap[(size_t)2 * HWSZ];
        float ay2 = ap[(size_t)3 * HWSZ];
        float aw  = ax2 - ax1;
        float ah  = ay2 - ay1;
        float acx = ax1 + 0.5f * aw;
        float acy = ay1 + 0.5f * ah;
        float dw = fminf(d2, DW_CLAMP);
        float dh = fminf(d3, DW_CLAMP);
        float gcx = acx + d0 * aw;
        float gcy = acy + d1 * ah;
        float gw  = aw * expf(dw);
        float gh  = ah * expf(dh);
        box.x = fminf(fmaxf(gcx - 0.5f * gw, 0.0f), IMG_WF);
        box.z = fminf(fmaxf(gcx + 0.5f * gw, 0.0f), IMG_WF);
        box.y = fminf(fmaxf(gcy - 0.5f * gh, 0.0f), IMG_HF);
        box.w = fminf(fmaxf(gcy + 0.5f * gh, 0.0f), IMG_HF);
    }
    topbox[(size_t)b * P2 + r] = box;
    tops  [(size_t)b * P2 + r] = sc;
    topcls[(size_t)b * P2 + r] = cl;
}

// ---------------- suppression bitmask: mask[i][w] bits over j --------
__global__ void __launch_bounds__(256) mask_kernel(const float4* __restrict__ topbox,
                                                   const float* __restrict__ tops,
                                                   u64* __restrict__ mask) {
    __shared__ float4 bx[P2];      // 32 KB
    __shared__ float2 sa[P2];      // (score, area) 16 KB
    int b    = blockIdx.x >> 5;
    int rblk = blockIdx.x & 31;    // 64 rows per block
    int tid  = threadIdx.x;
    for (int i = tid; i < P2; i += 256) {
        float4 bb = topbox[(size_t)b * P2 + i];
        bx[i] = bb;
        sa[i] = make_float2(tops[(size_t)b * P2 + i],
                            (bb.z - bb.x) * (bb.w - bb.y));
    }
    __syncthreads();
    int i  = rblk * 64 + (tid >> 2);
    int w0 = (tid & 3) * 8;
    float4 bi = bx[i];
    float  si = sa[i].x;
    float  ai = sa[i].y;
    for (int w = w0; w < w0 + 8; ++w) {
        u64 bits = 0ULL;
        #pragma unroll 8
        for (int jj = 0; jj < 64; ++jj) {
            int j = w * 64 + jj;
            float4 bj = bx[j];
            float2 sj = sa[j];
            float iw = fminf(bi.z, bj.z) - fmaxf(bi.x, bj.x);
            float ih = fminf(bi.w, bj.w) - fmaxf(bi.y, bj.y);
            iw = fmaxf(iw, 0.0f); ih = fmaxf(ih, 0.0f);
            float inter = iw * ih;
            float uni = fmaxf(ai + sj.y - inter, 1e-9f);
            float iou = inter / uni;                       // ref divides
            if (iou > IOU_THR && si > sj.x) bits |= (1ULL << jj);
        }
        mask[((size_t)b * P2 + i) * 32 + w] = bits;
    }
}

// ---------------- sequential greedy scan, 1 wave per image -----------
// Suppression is forward-only (descending scores + strict >), so a single
// ascending sweep over i reproduces the reference fori_loop exactly.
__global__ void __launch_bounds__(64) nms_scan_kernel(const u64* __restrict__ sel,
                                                      const u64* __restrict__ mask,
                                                      u64* __restrict__ keepout) {
    int b = blockIdx.x;
    int lane = threadIdx.x;          // lanes 0..31 own the 32 keep words
    if (lane < 32) {
        u64 keep = 0ULL;
        for (int j = 0; j < 64; ++j) {
            int idx = lane * 64 + j;
            u64 v = sel[(size_t)b * P2 + idx];
            if (idx < PRE_K && v != 0ULL) keep |= (1ULL << j);
        }
        const u64* mrow = mask + (size_t)b * P2 * 32 + lane;
        u64 bufA[32], bufB[32];
        #pragma unroll
        for (int k = 0; k < 32; ++k) bufA[k] = mrow[(size_t)k * 32];

        for (int cc = 0; cc < 32; ++cc) {
            int c0 = 2 * cc, c1 = 2 * cc + 1;
            // prefetch chunk c1 (overlaps with processing c0)
            #pragma unroll
            for (int k = 0; k < 32; ++k)
                bufB[k] = mrow[(size_t)(c1 * 32 + k) * 32];
            #pragma unroll
            for (int k = 0; k < 32; ++k) {
                int i = c0 * 32 + k;
                u64 kw = __shfl(keep, i >> 6);
                if ((kw >> (i & 63)) & 1ULL) keep &= ~bufA[k];
            }
            // prefetch chunk c0+2 (clamped) overlapping with processing c1
            int cn = (c0 + 2 < 64) ? (c0 + 2) : 63;
            #pragma unroll
            for (int k = 0; k < 32; ++k)
                bufA[k] = mrow[(size_t)(cn * 32 + k) * 32];
            #pragma unroll
            for (int k = 0; k < 32; ++k) {
                int i = c1 * 32 + k;
                u64 kw = __shfl(keep, i >> 6);
                if ((kw >> (i & 63)) & 1ULL) keep &= ~bufB[k];
            }
        }
        keepout[b * 32 + lane] = keep;
    }
}

// ---------------- final top-100 compaction + zero pad ----------------
__global__ void __launch_bounds__(256) out_kernel(const u64* __restrict__ keepw,
                                                  const float4* __restrict__ topbox,
                                                  const float* __restrict__ tops,
                                                  const int* __restrict__ topcls,
                                                  float* __restrict__ out) {
    __shared__ u64 kw[32];
    __shared__ u32 pre[32];
    int b = blockIdx.x, tid = threadIdx.x;
    if (tid < 32) kw[tid] = keepw[b * 32 + tid];
    __syncthreads();
    if (tid == 0) {
        u32 c = 0;
        for (int w = 0; w < 32; ++w) { pre[w] = c; c += (u32)__popcll(kw[w]); }
    }
    __syncthreads();
    float* ob = out;                          // [B][100][4]
    float* os = out + BB * POST_K * 4;        // [B][100]
    float* oc = out + BB * POST_K * 5;        // [B][100] (cls as float)
    if (tid < POST_K) {
        int base = b * POST_K + tid;
        ob[base * 4 + 0] = 0.f; ob[base * 4 + 1] = 0.f;
        ob[base * 4 + 2] = 0.f; ob[base * 4 + 3] = 0.f;
        os[base] = 0.f; oc[base] = 0.f;
    }
    __syncthreads();
    for (int i = tid; i < P2; i += 256) {
        int w = i >> 6, bit = i & 63;
        u64 word = kw[w];
        if ((word >> bit) & 1ULL) {
            u32 rank = pre[w] + (u32)__popcll(word & ((1ULL << bit) - 1ULL));
            if (rank < POST_K) {
                float4 bb = topbox[(size_t)b * P2 + i];
                int base = b * POST_K + (int)rank;
                ob[base * 4 + 0] = bb.x; ob[base * 4 + 1] = bb.y;
                ob[base * 4 + 2] = bb.z; ob[base * 4 + 3] = bb.w;
                os[base] = tops[(size_t)b * P2 + i];
                oc[base] = (float)topcls[(size_t)b * P2 + i];
            }
        }
    }
}

// ---------------- host launch ----------------------------------------
extern "C" void kernel_launch(void* const* d_in, const int* in_sizes, int n_in,
                              void* d_out, int out_size, void* d_ws, size_t ws_size,
                              hipStream_t stream) {
    (void)in_sizes; (void)n_in; (void)out_size; (void)ws_size;
    const float* anchors = (const float*)d_in[0];
    const float* head    = (const float*)d_in[1];
    float* out = (float*)d_out;
    char* ws = (char*)d_ws;

    // workspace layout (peak ≈5.73 MB).
    // mask ALIASES keys — keys' last read is compact_kernel, mask's first
    // write is mask_kernel (strictly later in-stream).
    u32* hist    = (u32*)(ws + 0);              // 3 levels * 8 * 256 u32
    u32* prefix  = (u32*)(ws + 24576);          // 8
    u32* need    = (u32*)(ws + 24608);          // 8
    u32* ccnt    = (u32*)(ws + 24640);          // 8 * CCNT_STRIDE (padded)
    u32* keys    = (u32*)(ws + 25856);          // 8*153600*4 B (16B aligned)
    u64* mask    = (u64*)(ws + 25856);          // 8*2048*32*8 B (aliases keys)
    u64* cand    = (u64*)(ws + 4941056);        // 8*4096*8 B
    u64* sel     = (u64*)(ws + 5203200);        // 8*2048*8 B
    float4* topbox = (float4*)(ws + 5334272);   // 8*2048*16 B
    float* tops  = (float*)(ws + 5596416);      // 8*2048*4 B
    int* topcls  = (int*)(ws + 5661952);        // 8*2048*4 B
    u64* keepw   = (u64*)(ws + 5727488);        // 8*32*8 B

    init_kernel<<<1, 256, 0, stream>>>((u32*)ws);
    decode_kernel<<<BB * NBLK4, 256, 0, stream>>>(anchors, head, keys, hist);
    select_kernel<<<BB, 256, 0, stream>>>(hist, prefix, need, 24);
    hist_kernel<<<BB * NBLK, 256, 0, stream>>>(keys, prefix, hist + BB * 256,
                                               0xFF000000u, 16);
    select_kernel<<<BB, 256, 0, stream>>>(hist + BB * 256, prefix, need, 16);
    hist_kernel<<<BB * NBLK, 256, 0, stream>>>(keys, prefix, hist + 2 * BB * 256,
                                               0xFFFF0000u, 8);
    select_kernel<<<BB, 256, 0, stream>>>(hist + 2 * BB * 256, prefix, need, 8);
    compact_kernel<<<BB * NBLK, 256, 0, stream>>>(keys, prefix, ccnt, cand);
    sort_kernel<<<BB, 1024, 0, stream>>>(cand, ccnt, sel);
    gather_kernel<<<BB * 8, 256, 0, stream>>>(anchors, head, sel, topbox, tops, topcls);
    mask_kernel<<<BB * 32, 256, 0, stream>>>(topbox, tops, mask);
    nms_scan_kernel<<<BB, 64, 0, stream>>>(sel, mask, keepw);
    out_kernel<<<BB, 256, 0, stream>>>(keepw, topbox, tops, topcls, out);
}

// Round 10
// 278.646 us; speedup vs baseline: 2.0270x; 1.5713x over previous
//
#include <hip/hip_runtime.h>
#include <cstdint>
#include <cstddef>

// ---------------- problem constants (mirror reference) ----------------
#define BB      8
#define AA      6
#define CCL     16          // classes
#define HH      160
#define WWW     160
#define HWSZ    (HH * WWW)          // 25600
#define NN      (AA * HWSZ)         // 153600 boxes per image
#define NBLK4   (NN / 1024)         // 150 blocks per image (uint4 passes)
#define PRE_K   2000
#define P2      2048                // padded PRE_K
#define CAP     4096                // compaction capacity per image
#define POST_K  100
#define SCORE_THR 0.05f
#define IOU_THR   0.5f
#define DW_CLAMP  4.0f
#define IMG_WF    1280.0f
#define IMG_HF    1280.0f
#define MIN_WF    2.0f
#define MIN_HF    2.0f

#define CCNT_STRIDE 32      // pad per-image atomic counters to 128 B (own line)

typedef unsigned int       u32;
typedef unsigned long long u64;

// ---------------- K0: zero ws control region -------------------------
// u32 idx: hist[3*8*256] @0; prefix[8] @6144; need[8] @6152;
//          ccnt[8*CCNT_STRIDE] @6160  (end 6416)
__global__ void init_kernel(u32* __restrict__ w) {
    int tid = threadIdx.x;
    for (int i = tid; i < 6416; i += 256) w[i] = 0u;
    __syncthreads();
    if (tid < BB) w[6152 + tid] = PRE_K;
}

// ---------------- K1: float4 decode + key write + level-0 histogram --
// sigmoid is monotone: max prob = sigmoid(max logit); cls is NOT needed
// here (only gather needs it), so a plain fmaxf chain suffices.
__global__ void __launch_bounds__(256) decode_kernel(const float* __restrict__ anchors,
                                                     const float* __restrict__ head,
                                                     u32* __restrict__ keys,
                                                     u32* __restrict__ hist1) {
    __shared__ u32 h[256];
    int tid = threadIdx.x;
    h[tid] = 0u;
    __syncthreads();
    int blk = blockIdx.x;
    int b  = blk / NBLK4;
    int e0 = ((blk - b * NBLK4) * 256 + tid) * 4;   // 4 consecutive hw cells
    int a  = e0 / HWSZ;                              // all 4 in same channel row
    int hw = e0 - a * HWSZ;
    const int CS = HWSZ / 4;                         // float4 channel stride
    const float4* hp = (const float4*)(head +
        (((size_t)b * AA + a) * (4 + CCL)) * HWSZ + hw);
    const float4* ap = (const float4*)(anchors + (size_t)a * 4 * HWSZ + hw);

    float4 d0 = hp[0];
    float4 d1 = hp[CS];
    float4 d2 = hp[2 * CS];
    float4 d3 = hp[3 * CS];

    float4 bl = make_float4(-1e30f, -1e30f, -1e30f, -1e30f);
    #pragma unroll
    for (int k = 0; k < CCL; ++k) {
        float4 lv = hp[(4 + k) * CS];
        bl.x = fmaxf(bl.x, lv.x);
        bl.y = fmaxf(bl.y, lv.y);
        bl.z = fmaxf(bl.z, lv.z);
        bl.w = fmaxf(bl.w, lv.w);
    }

    float4 ax1 = ap[0];
    float4 ay1 = ap[CS];
    float4 ax2 = ap[2 * CS];
    float4 ay2 = ap[3 * CS];

    u32 k4[4];
    #pragma unroll
    for (int j = 0; j < 4; ++j) {
        float dj0 = (&d0.x)[j];
        float dj1 = (&d1.x)[j];
        float dj2 = (&d2.x)[j];
        float dj3 = (&d3.x)[j];
        float x1a = (&ax1.x)[j], y1a = (&ay1.x)[j];
        float x2a = (&ax2.x)[j], y2a = (&ay2.x)[j];
        float blj = (&bl.x)[j];

        float best = 1.0f / (1.0f + expf(-blj));   // IEEE div, accurate expf

        float aw  = x2a - x1a;
        float ah  = y2a - y1a;
        float acx = x1a + 0.5f * aw;
        float acy = y1a + 0.5f * ah;
        float dw = fminf(dj2, DW_CLAMP);
        float dh = fminf(dj3, DW_CLAMP);
        float gcx = acx + dj0 * aw;
        float gcy = acy + dj1 * ah;
        float gw  = aw * expf(dw);
        float gh  = ah * expf(dh);
        float x1 = fminf(fmaxf(gcx - 0.5f * gw, 0.0f), IMG_WF);
        float x2 = fminf(fmaxf(gcx + 0.5f * gw, 0.0f), IMG_WF);
        float y1 = fminf(fmaxf(gcy - 0.5f * gh, 0.0f), IMG_HF);
        float y2 = fminf(fmaxf(gcy + 0.5f * gh, 0.0f), IMG_HF);

        bool valid = (best >= SCORE_THR) && ((x2 - x1) >= MIN_WF) &&
                     ((y2 - y1) >= MIN_HF);
        k4[j] = valid ? __float_as_uint(best) : 0u;  // score>0 -> bits monotone
    }

    *(uint4*)(keys + (size_t)b * NN + e0) = make_uint4(k4[0], k4[1], k4[2], k4[3]);

    // per-thread bin merge (scores concentrate in few top-byte bins)
    #pragma unroll
    for (int j = 0; j < 4; ++j) {
        if (!k4[j]) continue;
        u32 bin = k4[j] >> 24;
        bool dup = false;
        #pragma unroll
        for (int l = 0; l < 4; ++l)
            if (l < j) dup |= (k4[l] != 0u) && ((k4[l] >> 24) == bin);
        if (!dup) {
            u32 c = 1;
            #pragma unroll
            for (int l = 0; l < 4; ++l)
                if (l > j) c += ((k4[l] != 0u) && ((k4[l] >> 24) == bin)) ? 1u : 0u;
            atomicAdd(&h[bin], c);
        }
    }
    __syncthreads();
    if (h[tid]) atomicAdd(&hist1[b * 256 + tid], h[tid]);
}

// ---------------- histogram of one refinement digit (uint4) ----------
__global__ void __launch_bounds__(256) hist_kernel(const u32* __restrict__ keys,
                                                   const u32* __restrict__ prefix,
                                                   u32* __restrict__ hist,
                                                   u32 pmask, int shift) {
    __shared__ u32 h[256];
    int tid = threadIdx.x;
    h[tid] = 0u;
    __syncthreads();
    int blk = blockIdx.x;
    int b  = blk / NBLK4;
    int e0 = ((blk - b * NBLK4) * 256 + tid) * 4;
    uint4 v = *(const uint4*)(keys + (size_t)b * NN + e0);
    u32 pfx = prefix[b] & pmask;
    u32 kk[4] = {v.x, v.y, v.z, v.w};
    #pragma unroll
    for (int q = 0; q < 4; ++q)
        if (kk[q] != 0u && (kk[q] & pmask) == pfx)
            atomicAdd(&h[(kk[q] >> shift) & 255u], 1u);
    __syncthreads();
    if (h[tid]) atomicAdd(&hist[b * 256 + tid], h[tid]);
}

// ---------------- pick digit where descending cumsum crosses `need` ---
// Bit-identical semantics to the serial loop (see R4 notes).
__global__ void __launch_bounds__(256) select_kernel(const u32* __restrict__ hist,
                                                     u32* __restrict__ prefix,
                                                     u32* __restrict__ need,
                                                     int shift) {
    __shared__ u32 a[256];
    __shared__ int best;
    int t = threadIdx.x;
    int b = blockIdx.x;
    u32 nd = need[b];
    u32 myc = hist[b * 256 + t];
    a[t] = myc;
    if (t == 0) best = 0;
    __syncthreads();
    for (int s = 1; s < 256; s <<= 1) {
        u32 v = a[t] + ((t + s < 256) ? a[t + s] : 0u);
        __syncthreads();
        a[t] = v;
        __syncthreads();
    }
    if (t >= 1 && a[t] >= nd) atomicMax(&best, t);
    __syncthreads();
    if (t == best) {
        if (t >= 1) {
            prefix[b] |= ((u32)t) << shift;
            need[b] = nd - (a[t] - myc);
        } else {
            need[b] = nd - a[1];   // no bin e>=1 crossed: d=0, cum = U[1]
        }
    }
}

// ---------------- compact keys >= threshold (uint4, 1 atomic/block) --
// Within-cand order is arbitrary: the sort's (key,~idx) total order makes
// the final ranking deterministic regardless.
__global__ void __launch_bounds__(256) compact_kernel(const u32* __restrict__ keys,
                                                      const u32* __restrict__ prefix,
                                                      u32* __restrict__ ccnt,
                                                      u64* __restrict__ cand) {
    __shared__ u32 cnt16[16];
    __shared__ u32 off16[16];
    __shared__ u32 sbase;
    int blk = blockIdx.x;
    int b   = blk / NBLK4;
    int tid = threadIdx.x;
    int lane = tid & 63, wid = tid >> 6;
    int e0 = ((blk - b * NBLK4) * 256 + tid) * 4;
    uint4 v = *(const uint4*)(keys + (size_t)b * NN + e0);
    u32 T = prefix[b];
    u32 kk[4] = {v.x, v.y, v.z, v.w};
    bool p[4]; u32 rk[4];
    #pragma unroll
    for (int q = 0; q < 4; ++q) {
        p[q] = (kk[q] != 0u) && (kk[q] >= T);
        u64 bal = __ballot(p[q]);
        rk[q] = (u32)__popcll(bal & ((1ull << lane) - 1ull));
        if (lane == 0) cnt16[q * 4 + wid] = (u32)__popcll(bal);
    }
    __syncthreads();
    if (tid == 0) {
        u32 c = 0;
        #pragma unroll
        for (int i = 0; i < 16; ++i) { off16[i] = c; c += cnt16[i]; }
        sbase = c ? atomicAdd(&ccnt[b * CCNT_STRIDE], c) : 0u;
    }
    __syncthreads();
    #pragma unroll
    for (int q = 0; q < 4; ++q) {
        if (p[q]) {
            u32 pos = sbase + off16[q * 4 + wid] + rk[q];
            if (pos < CAP)
                cand[(size_t)b * CAP + pos] =
                    ((u64)kk[q] << 32) | (u32)(~(u32)(e0 + q));
        }
    }
}

// ---------------- bitonic sort in LDS (ascending on ~v) --------------
// Dynamic network size: 2048 when ccnt<=2048 (common), else 4096.
__global__ void __launch_bounds__(1024) sort_kernel(const u64* __restrict__ cand,
                                                    const u32* __restrict__ ccnt,
                                                    u64* __restrict__ sel) {
    __shared__ u64 sm[CAP];
    int b = blockIdx.x, tid = threadIdx.x;
    u32 n = ccnt[b * CCNT_STRIDE]; if (n > CAP) n = CAP;
    int M = (n <= 2048) ? 2048 : CAP;
    for (int i = tid; i < M; i += 1024)
        sm[i] = (i < (int)n) ? ~cand[(size_t)b * CAP + i] : ~0ULL;
    __syncthreads();
    for (int k = 2; k <= M; k <<= 1) {
        for (int j = k >> 1; j > 0; j >>= 1) {
            for (int i = tid; i < M; i += 1024) {
                int ixj = i ^ j;
                if (ixj > i) {
                    u64 a = sm[i], c = sm[ixj];
                    bool up = ((i & k) == 0);
                    if (up ? (a > c) : (a < c)) { sm[i] = c; sm[ixj] = a; }
                }
            }
            __syncthreads();
        }
    }
    for (int r = tid; r < P2; r += 1024)
        sel[(size_t)b * P2 + r] = ~sm[r];
}

// ---------------- gather-decode the selected 2000 --------------------
// score comes FROM the key bits (bit-identical to sort order); box & cls
// are decoded fresh (reference-identical expressions).
__global__ void __launch_bounds__(256) gather_kernel(const float* __restrict__ anchors,
                                                     const float* __restrict__ head,
                                                     const u64* __restrict__ sel,
                                                     float4* __restrict__ topbox,
                                                     float* __restrict__ tops,
                                                     int* __restrict__ topcls) {
    int b = blockIdx.x >> 3;
    int r = (blockIdx.x & 7) * 256 + threadIdx.x;
    u64 v = sel[(size_t)b * P2 + r];
    float4 box = make_float4(0.f, 0.f, 0.f, 0.f);
    float sc = -1.0f; int cl = 0;
    if (v != 0ULL && r < PRE_K) {   // ranks >= PRE_K are outside ref's top_k
        int n = (int)(~(u32)v);
        sc = __uint_as_float((u32)(v >> 32));

        int a  = n / HWSZ;
        int hw = n - a * HWSZ;
        const float* hp = head + (((size_t)b * AA + a) * (4 + CCL)) * HWSZ + hw;
        float d0 = hp[0];
        float d1 = hp[(size_t)1 * HWSZ];
        float d2 = hp[(size_t)2 * HWSZ];
        float d3 = hp[(size_t)3 * HWSZ];

        float blv = -1e30f; int bc = 0;
        #pragma unroll
        for (int k = 0; k < CCL; ++k) {
            float l = hp[(size_t)(4 + k) * HWSZ];
            if (l > blv) { blv = l; bc = k; }
        }
        cl = bc;

        const float* ap = anchors + (size_t)a * 4 * HWSZ + hw;
        float ax1 = ap[0];
        float ay1 = ap[(size_t)1 * HWSZ];
        float ax2 = ap[(size_t)2 * HWSZ];
        float ay2 = ap[(size_t)3 * HWSZ];
        float aw  = ax2 - ax1;
        float ah  = ay2 - ay1;
        float acx = ax1 + 0.5f * aw;
        float acy = ay1 + 0.5f * ah;
        float dw = fminf(d2, DW_CLAMP);
        float dh = fminf(d3, DW_CLAMP);
        float gcx = acx + d0 * aw;
        float gcy = acy + d1 * ah;
        float gw  = aw * expf(dw);
        float gh  = ah * expf(dh);
        box.x = fminf(fmaxf(gcx - 0.5f * gw, 0.0f), IMG_WF);
        box.z = fminf(fmaxf(gcx + 0.5f * gw, 0.0f), IMG_WF);
        box.y = fminf(fmaxf(gcy - 0.5f * gh, 0.0f), IMG_HF);
        box.w = fminf(fmaxf(gcy + 0.5f * gh, 0.0f), IMG_HF);
    }
    topbox[(size_t)b * P2 + r] = box;
    tops  [(size_t)b * P2 + r] = sc;
    topcls[(size_t)b * P2 + r] = cl;
}

// ---------------- suppression bitmask: mask[i][w] bits over j --------
// Scores are non-increasing over rank, so si > sj is false for j <= i:
// words w < rblk are identically zero -> store 0 without computing.
__global__ void __launch_bounds__(256) mask_kernel(const float4* __restrict__ topbox,
                                                   const float* __restrict__ tops,
                                                   u64* __restrict__ mask) {
    __shared__ float4 bx[P2];      // 32 KB
    __shared__ float2 sa[P2];      // (score, area) 16 KB
    int b    = blockIdx.x >> 5;
    int rblk = blockIdx.x & 31;    // 64 rows per block
    int tid  = threadIdx.x;
    for (int i = tid; i < P2; i += 256) {
        float4 bb = topbox[(size_t)b * P2 + i];
        bx[i] = bb;
        sa[i] = make_float2(tops[(size_t)b * P2 + i],
                            (bb.z - bb.x) * (bb.w - bb.y));
    }
    __syncthreads();
    int i  = rblk * 64 + (tid >> 2);
    int w0 = (tid & 3) * 8;
    float4 bi = bx[i];
    float  si = sa[i].x;
    float  ai = sa[i].y;
    for (int w = w0; w < w0 + 8; ++w) {
        u64 bits = 0ULL;
        if (w >= rblk) {
            #pragma unroll 8
            for (int jj = 0; jj < 64; ++jj) {
                int j = w * 64 + jj;
                float4 bj = bx[j];
                float2 sj = sa[j];
                float iw = fminf(bi.z, bj.z) - fmaxf(bi.x, bj.x);
                float ih = fminf(bi.w, bj.w) - fmaxf(bi.y, bj.y);
                iw = fmaxf(iw, 0.0f); ih = fmaxf(ih, 0.0f);
                float inter = iw * ih;
                float uni = fmaxf(ai + sj.y - inter, 1e-9f);
                float iou = inter / uni;                   // ref divides
                if (iou > IOU_THR && si > sj.x) bits |= (1ULL << jj);
            }
        }
        mask[((size_t)b * P2 + i) * 32 + w] = bits;
    }
}

// ------- fused greedy scan (group-broadcast, early-exit) + output ----
// mask[i] has zero bits at positions j<=i (forward-only suppression).
// Per group g: one shfl gets the live keep word; the 64-step chain runs
// redundantly in all lanes on values broadcast from lane g; owner lanes
// AND their own column buffers. After group g, words 0..g are FINAL.
// Output only uses the first POST_K kept (prefix-ranked), so once the
// running popcount of finalized words reaches POST_K we can stop: all
// later (possibly stale) bits rank >= POST_K and are skipped below.
#define NMS_LOAD16(BUF, R0)                                   \
    _Pragma("unroll")                                         \
    for (int k_ = 0; k_ < 16; ++k_) {                         \
        int r_ = (R0) + k_; r_ = r_ < 2047 ? r_ : 2047;       \
        BUF[k_] = mbase[(size_t)r_ * 32];                     \
    }
#define NMS_PROC16(BUF, O)                                    \
    _Pragma("unroll")                                         \
    for (int j_ = 0; j_ < 16; ++j_) {                         \
        u64 m_ = __shfl(BUF[j_], g);                          \
        if ((kw >> ((O) + j_)) & 1ULL) kw &= ~m_;             \
    }                                                         \
    _Pragma("unroll")                                         \
    for (int j_ = 0; j_ < 16; ++j_) {                         \
        u64 s_ = ((kw >> ((O) + j_)) & 1ULL) ? BUF[j_] : 0ULL;\
        keep &= ~s_;                                          \
    }

__global__ void __launch_bounds__(64) nms_out_kernel(const u64* __restrict__ sel,
                                                     const u64* __restrict__ mask,
                                                     const float4* __restrict__ topbox,
                                                     const float* __restrict__ tops,
                                                     const int* __restrict__ topcls,
                                                     float* __restrict__ out) {
    __shared__ u64 kws[32];
    __shared__ u32 pre[32];
    int b = blockIdx.x;
    int lane = threadIdx.x;          // lanes 0..31 own keep words
    // ballot keep-init: iteration t covers rows t*64..t*64+63 == word t
    u64 keep = 0ULL;
    for (int t = 0; t < 32; ++t) {
        int idx = t * 64 + lane;
        u64 v = sel[(size_t)b * P2 + idx];
        u64 bal = __ballot((idx < PRE_K) && (v != 0ULL));
        if (lane == t) keep = bal;
    }
    const u64* mbase = mask + (size_t)b * P2 * 32 + (lane & 31);
    u64 bufA[16], bufB[16];
    u32 total = 0;
    NMS_LOAD16(bufA, 0);
    for (int g = 0; g < 32; ++g) {
        int r0 = g * 64;
        u64 kw = __shfl(keep, g);    // live word g (groups <g all applied)
        NMS_LOAD16(bufB, r0 + 16);
        NMS_PROC16(bufA, 0);
        NMS_LOAD16(bufA, r0 + 32);
        NMS_PROC16(bufB, 16);
        NMS_LOAD16(bufB, r0 + 48);
        NMS_PROC16(bufA, 32);
        NMS_LOAD16(bufA, r0 + 64);   // next group's first batch (clamped)
        NMS_PROC16(bufB, 48);
        total += (u32)__popcll(kw);  // kw is wave-uniform and final
        if (total >= POST_K) break;  // uniform branch
    }
    if (lane < 32) kws[lane] = keep;
    __syncthreads();
    if (lane == 0) {
        u32 c = 0;
        for (int w = 0; w < 32; ++w) { pre[w] = c; c += (u32)__popcll(kws[w]); }
    }
    __syncthreads();
    // zero-pad outputs
    float* ob = out;                          // [B][100][4]
    float* os = out + BB * POST_K * 4;        // [B][100]
    float* oc = out + BB * POST_K * 5;        // [B][100] (cls as float)
    for (int t = lane; t < POST_K; t += 64) {
        int base = b * POST_K + t;
        ob[base * 4 + 0] = 0.f; ob[base * 4 + 1] = 0.f;
        ob[base * 4 + 2] = 0.f; ob[base * 4 + 3] = 0.f;
        os[base] = 0.f; oc[base] = 0.f;
    }
    __syncthreads();
    for (int i = lane; i < P2; i += 64) {
        int w = i >> 6, bit = i & 63;
        u64 word = kws[w];
        if ((word >> bit) & 1ULL) {
            u32 rank = pre[w] + (u32)__popcll(word & ((1ULL << bit) - 1ULL));
            if (rank < POST_K) {
                float4 bb = topbox[(size_t)b * P2 + i];
                int base = b * POST_K + (int)rank;
                ob[base * 4 + 0] = bb.x; ob[base * 4 + 1] = bb.y;
                ob[base * 4 + 2] = bb.z; ob[base * 4 + 3] = bb.w;
                os[base] = tops[(size_t)b * P2 + i];
                oc[base] = (float)topcls[(size_t)b * P2 + i];
            }
        }
    }
}

// ---------------- host launch ----------------------------------------
extern "C" void kernel_launch(void* const* d_in, const int* in_sizes, int n_in,
                              void* d_out, int out_size, void* d_ws, size_t ws_size,
                              hipStream_t stream) {
    (void)in_sizes; (void)n_in; (void)out_size; (void)ws_size;
    const float* anchors = (const float*)d_in[0];
    const float* head    = (const float*)d_in[1];
    float* out = (float*)d_out;
    char* ws = (char*)d_ws;

    // workspace layout (peak ≈5.73 MB).
    // mask ALIASES keys — keys' last read is compact_kernel, mask's first
    // write is mask_kernel (strictly later in-stream).
    u32* hist    = (u32*)(ws + 0);              // 3 levels * 8 * 256 u32
    u32* prefix  = (u32*)(ws + 24576);          // 8
    u32* need    = (u32*)(ws + 24608);          // 8
    u32* ccnt    = (u32*)(ws + 24640);          // 8 * CCNT_STRIDE (padded)
    u32* keys    = (u32*)(ws + 25856);          // 8*153600*4 B (16B aligned)
    u64* mask    = (u64*)(ws + 25856);          // 8*2048*32*8 B (aliases keys)
    u64* cand    = (u64*)(ws + 4941056);        // 8*4096*8 B
    u64* sel     = (u64*)(ws + 5203200);        // 8*2048*8 B
    float4* topbox = (float4*)(ws + 5334272);   // 8*2048*16 B
    float* tops  = (float*)(ws + 5596416);      // 8*2048*4 B
    int* topcls  = (int*)(ws + 5661952);        // 8*2048*4 B

    init_kernel<<<1, 256, 0, stream>>>((u32*)ws);
    decode_kernel<<<BB * NBLK4, 256, 0, stream>>>(anchors, head, keys, hist);
    select_kernel<<<BB, 256, 0, stream>>>(hist, prefix, need, 24);
    hist_kernel<<<BB * NBLK4, 256, 0, stream>>>(keys, prefix, hist + BB * 256,
                                                0xFF000000u, 16);
    select_kernel<<<BB, 256, 0, stream>>>(hist + BB * 256, prefix, need, 16);
    hist_kernel<<<BB * NBLK4, 256, 0, stream>>>(keys, prefix, hist + 2 * BB * 256,
                                                0xFFFF0000u, 8);
    select_kernel<<<BB, 256, 0, stream>>>(hist + 2 * BB * 256, prefix, need, 8);
    compact_kernel<<<BB * NBLK4, 256, 0, stream>>>(keys, prefix, ccnt, cand);
    sort_kernel<<<BB, 1024, 0, stream>>>(cand, ccnt, sel);
    gather_kernel<<<BB * 8, 256, 0, stream>>>(anchors, head, sel, topbox, tops, topcls);
    mask_kernel<<<BB * 32, 256, 0, stream>>>(topbox, tops, mask);
    nms_out_kernel<<<BB, 64, 0, stream>>>(sel, mask, topbox, tops, topcls, out);
}